// Round 8
// baseline (445.348 us; speedup 1.0000x reference)
//
#include <hip/hip_runtime.h>
#include <hip/hip_bf16.h>

typedef unsigned short u16;
typedef __attribute__((ext_vector_type(8))) __bf16 bf16x8;
typedef __attribute__((ext_vector_type(4))) float f32x4;
typedef __attribute__((ext_vector_type(2))) unsigned int u32x2;

#define MODEL_DIM 1024
#define NUM_HEADS 16
#define HEAD_DIM  64
#define BATCH     4
#define SEQ       2048
#define ROWS      (BATCH*SEQ)     // 8192

static __device__ __forceinline__ u16 f2bf(float f) {
    union { __hip_bfloat16 h; u16 u; } cv;
    cv.h = __float2bfloat16(f);
    return cv.u;
}

static __device__ __forceinline__ void gload16(const u16* g, unsigned lds_byte) {
    __builtin_amdgcn_global_load_lds(
        (const __attribute__((address_space(1))) unsigned int*)g,
        (__attribute__((address_space(3))) unsigned int*)(uintptr_t)lds_byte,
        16, 0, 0);
}

// ---------------- fused cast f32 -> bf16 (x + 4 weights, contiguous out) ----
__global__ void castk_all(const float* __restrict__ x,
                          const float* __restrict__ w0, const float* __restrict__ w1,
                          const float* __restrict__ w2, const float* __restrict__ w3,
                          u16* __restrict__ out) {
    const int total = ROWS * MODEL_DIM + 4 * MODEL_DIM * MODEL_DIM;  // 12.58M
    int i = (blockIdx.x * blockDim.x + threadIdx.x) * 4;
    int stride = gridDim.x * blockDim.x * 4;
    for (; i < total; i += stride) {
        const float* src;
        int off;
        if (i < ROWS * MODEL_DIM) { src = x; off = i; }
        else {
            int j = i - ROWS * MODEL_DIM;
            int w = j >> 20;
            off = j & 1048575;
            src = (w == 0) ? w0 : (w == 1) ? w1 : (w == 2) ? w2 : w3;
        }
        float4 v = *reinterpret_cast<const float4*>(src + off);
        ushort4 o;
        o.x = f2bf(v.x); o.y = f2bf(v.y); o.z = f2bf(v.z); o.w = f2bf(v.w);
        *reinterpret_cast<ushort4*>(out + i) = o;
    }
}

// ---------------- NT GEMM core (gload_lds + XOR-swizzle staging) ----------
#define BM 128
#define BN 128
#define BK 64

// stage a 128x64 bf16 tile (row stride K) into LDS via global_load_lds with
// pre-swizzled source: LDS byte (row, b) holds global col-byte b^((row&7)<<4).
static __device__ __forceinline__ void stage_tile(const u16* gbase, int K,
                                                  unsigned lds_byte_base, int t) {
#pragma unroll
    for (int ti = 0; ti < 4; ti++) {
        int o    = t * 8 + ti * 2048;
        int row  = o >> 6;
        int colb = ((o & 63) * 2) ^ ((row & 7) << 4);
        gload16(gbase + (size_t)row * K + (colb >> 1), lds_byte_base + o * 2);
    }
}

// swizzled fragment read: rows (r16+lo), global byte-col (h*64+hi*16)
static __device__ __forceinline__ bf16x8 frag_read(const char* base, int row, int h,
                                                   int lo, int hi) {
    return *reinterpret_cast<const bf16x8*>(
        base + row * 128 + ((h * 64 + hi * 16) ^ ((lo & 7) << 4)));
}

// fused QKV projection: grid (M/128, 24); blockIdx.y selects matrix + col block
// Q output is pre-scaled by 0.125*log2(e) (softmax scale folded out of attn).
__global__ __launch_bounds__(256) void gemm_qkv(
    const u16* __restrict__ A,
    const u16* __restrict__ Wq, const u16* __restrict__ Wk, const u16* __restrict__ Wv,
    u16* __restrict__ qO, u16* __restrict__ kO, u16* __restrict__ vO)
{
    __shared__ u16 As[BM * BK];
    __shared__ u16 Bs[BN * BK];
    const int t    = threadIdx.x;
    const int wid  = t >> 6;
    const int lane = t & 63;
    const int lo   = lane & 15, hi = lane >> 4;
    const int bm   = blockIdx.x * BM;
    const int mat  = blockIdx.y >> 3;
    const int bn   = (blockIdx.y & 7) * BN;
    const u16* W   = (mat == 0) ? Wq : (mat == 1) ? Wk : Wv;
    u16* outB      = (mat == 0) ? qO : (mat == 1) ? kO : vO;
    const float qscale = (mat == 0) ? 0.18033688f : 1.0f;   // 0.125*log2(e)
    const int wr   = wid >> 1, wc = wid & 1;
    const int K = MODEL_DIM;
    const unsigned AsB = (unsigned)(uintptr_t)As;
    const unsigned BsB = (unsigned)(uintptr_t)Bs;

    f32x4 acc[4][4];
#pragma unroll
    for (int m = 0; m < 4; m++)
#pragma unroll
        for (int n = 0; n < 4; n++) acc[m][n] = (f32x4){0.f, 0.f, 0.f, 0.f};

    for (int k0 = 0; k0 < K; k0 += BK) {
        __syncthreads();
        stage_tile(A + (size_t)bm * K + k0, K, AsB, t);
        stage_tile(W + (size_t)bn * K + k0, K, BsB, t);
        __syncthreads();   // compiler drains vmcnt before s_barrier
#pragma unroll
        for (int h = 0; h < 2; h++) {
            bf16x8 af[4], bfr[4];
#pragma unroll
            for (int m = 0; m < 4; m++)
                af[m] = frag_read((const char*)As, wr * 64 + m * 16 + lo, h, lo, hi);
#pragma unroll
            for (int n = 0; n < 4; n++)
                bfr[n] = frag_read((const char*)Bs, wc * 64 + n * 16 + lo, h, lo, hi);
#pragma unroll
            for (int m = 0; m < 4; m++)
#pragma unroll
                for (int n = 0; n < 4; n++)
                    acc[m][n] = __builtin_amdgcn_mfma_f32_16x16x32_bf16(af[m], bfr[n], acc[m][n], 0, 0, 0);
        }
    }

#pragma unroll
    for (int m = 0; m < 4; m++)
#pragma unroll
        for (int n = 0; n < 4; n++)
#pragma unroll
            for (int r = 0; r < 4; r++) {
                int row = bm + wr * 64 + m * 16 + hi * 4 + r;
                int col = bn + wc * 64 + n * 16 + lo;
                int b = row >> 11, np = row & 2047;
                int hh = col >> 6, dd = col & 63;
                outB[(((size_t)(b * NUM_HEADS + hh) * SEQ + np) << 6) + dd] = f2bf(acc[m][n][r] * qscale);
            }
}

// out-projection: C = A * Wo^T + bias, f32 out
__global__ __launch_bounds__(256) void gemm_out(
    const u16* __restrict__ A,
    const u16* __restrict__ W,
    float* __restrict__ outF,
    const float* __restrict__ bias)
{
    __shared__ u16 As[BM * BK];
    __shared__ u16 Bs[BN * BK];
    const int t    = threadIdx.x;
    const int wid  = t >> 6;
    const int lane = t & 63;
    const int lo   = lane & 15, hi = lane >> 4;
    const int bm   = blockIdx.x * BM;
    const int bn   = blockIdx.y * BN;
    const int wr   = wid >> 1, wc = wid & 1;
    const int K = MODEL_DIM, N = MODEL_DIM;
    const unsigned AsB = (unsigned)(uintptr_t)As;
    const unsigned BsB = (unsigned)(uintptr_t)Bs;

    f32x4 acc[4][4];
#pragma unroll
    for (int m = 0; m < 4; m++)
#pragma unroll
        for (int n = 0; n < 4; n++) acc[m][n] = (f32x4){0.f, 0.f, 0.f, 0.f};

    for (int k0 = 0; k0 < K; k0 += BK) {
        __syncthreads();
        stage_tile(A + (size_t)bm * K + k0, K, AsB, t);
        stage_tile(W + (size_t)bn * K + k0, K, BsB, t);
        __syncthreads();
#pragma unroll
        for (int h = 0; h < 2; h++) {
            bf16x8 af[4], bfr[4];
#pragma unroll
            for (int m = 0; m < 4; m++)
                af[m] = frag_read((const char*)As, wr * 64 + m * 16 + lo, h, lo, hi);
#pragma unroll
            for (int n = 0; n < 4; n++)
                bfr[n] = frag_read((const char*)Bs, wc * 64 + n * 16 + lo, h, lo, hi);
#pragma unroll
            for (int m = 0; m < 4; m++)
#pragma unroll
                for (int n = 0; n < 4; n++)
                    acc[m][n] = __builtin_amdgcn_mfma_f32_16x16x32_bf16(af[m], bfr[n], acc[m][n], 0, 0, 0);
        }
    }

#pragma unroll
    for (int m = 0; m < 4; m++)
#pragma unroll
        for (int n = 0; n < 4; n++)
#pragma unroll
            for (int r = 0; r < 4; r++) {
                int row = bm + wr * 64 + m * 16 + hi * 4 + r;
                int col = bn + wc * 64 + n * 16 + lo;
                outF[(size_t)row * N + col] = acc[m][n][r] + bias[col];
            }
}

// ---------------- flash attention v7 -------------------------------------
// v6 structure + T14 reg-staged prefetch: issue tile j+1's global loads into
// regs BEFORE compute(j); ds_write after the post-compute barrier (vmcnt wait
// hidden under QK^T+softmax+PV). Single 16KB LDS buffer, 8 blocks/CU kept.

static __device__ __forceinline__ u32x2 tr16(unsigned int addr) {
    u32x2 r;
    asm volatile("ds_read_b64_tr_b16 %0, %1" : "=v"(r) : "v"(addr));
    return r;
}

__global__ __launch_bounds__(256, 8) void attn(
    const u16* __restrict__ Q,   // [B*H][N][64]
    const u16* __restrict__ Kg,
    const u16* __restrict__ Vg,
    u16* __restrict__ O)         // [B][N][H*64]
{
    // LDS (bytes): K swizzled @0 (8192), V subtiled @8192 (8192) = 16KB
    __shared__ u16 lds[8192];
    const int t    = threadIdx.x;
    const int wid  = t >> 6, lane = t & 63;
    const int lo   = lane & 15, hi = lane >> 4;

    const int g    = blockIdx.x;             // 0..2047
    const int slot = g >> 3;                 // 0..255
    const int bh   = ((slot & 7) << 3) + (g & 7);
    const int a    = slot >> 3;              // 0..31
    const int u    = a >> 2, a0 = a & 3;
    const int qt   = 4 * u + ((u & 1) ? 3 - a0 : a0);

    const size_t base = (size_t)bh * SEQ * 64;
    const int qbase = qt * 64 + wid * 16;
    const unsigned ldsb = (unsigned)(uintptr_t)lds;

    // staging geometry (identical to v6): per-lane swizzled/subtiled sources,
    // linear LDS dests; now written via reg round-trip for prefetch overlap.
    int sK[2], sV[2];
    unsigned dKb[2], dVb[2];
#pragma unroll
    for (int ti = 0; ti < 2; ti++) {
        int o   = t * 8 + ti * 2048;
        int row = o >> 6;
        int colb = ((o & 63) * 2) ^ ((row & 7) << 4);
        sK[ti] = row * 64 + (colb >> 1);
        dKb[ti] = o * 2;
        int st = o >> 9;
        int kv = (st >> 2) * 32 + ((o >> 4) & 31);
        int d  = (st & 3) * 16 + (o & 15);
        sV[ti] = kv * 64 + d;
        dVb[ti] = 8192 + o * 2;
    }

    // Q fragments (B-operand): lane holds Q[qbase+lo][h*32+hi*8+..] (pre-scaled)
    bf16x8 qf[2];
#pragma unroll
    for (int h = 0; h < 2; h++)
        qf[h] = *reinterpret_cast<const bf16x8*>(Q + base + (size_t)(qbase + lo) * 64 + h * 32 + hi * 8);
    asm volatile("" : "+v"(qf[0]), "+v"(qf[1]));

    float m_run = -3.0e38f, l_part = 0.f;
    f32x4 acc[4];
#pragma unroll
    for (int dt = 0; dt < 4; dt++) acc[dt] = (f32x4){0.f, 0.f, 0.f, 0.f};

    // prologue: reg-load tile 0, write LDS (visible at first loop barrier)
    {
        const u16* Kt = Kg + base;
        const u16* Vt = Vg + base;
        uint4 k0r = *reinterpret_cast<const uint4*>(Kt + sK[0]);
        uint4 k1r = *reinterpret_cast<const uint4*>(Kt + sK[1]);
        uint4 v0r = *reinterpret_cast<const uint4*>(Vt + sV[0]);
        uint4 v1r = *reinterpret_cast<const uint4*>(Vt + sV[1]);
        *reinterpret_cast<uint4*>((char*)lds + dKb[0]) = k0r;
        *reinterpret_cast<uint4*>((char*)lds + dKb[1]) = k1r;
        *reinterpret_cast<uint4*>((char*)lds + dVb[0]) = v0r;
        *reinterpret_cast<uint4*>((char*)lds + dVb[1]) = v1r;
    }

    for (int j = 0; j <= qt; j++) {
        // prefetch tile j+1 into registers (latency hides under compute)
        uint4 pk0, pk1, pv0, pv1;
        const bool pf = (j < qt);
        if (pf) {
            const u16* Kt = Kg + base + (size_t)(j + 1) * 4096;
            const u16* Vt = Vg + base + (size_t)(j + 1) * 4096;
            pk0 = *reinterpret_cast<const uint4*>(Kt + sK[0]);
            pk1 = *reinterpret_cast<const uint4*>(Kt + sK[1]);
            pv0 = *reinterpret_cast<const uint4*>(Vt + sV[0]);
            pv1 = *reinterpret_cast<const uint4*>(Vt + sV[1]);
        }
        __syncthreads();    // tile j (prev iter's ds_writes / prologue) visible

        // S^T = K Q^T: lane holds S[q=qbase+lo][kv=j*64+kt*16+hi*4+r]
        f32x4 s[4];
#pragma unroll
        for (int kh = 0; kh < 2; kh++) {
            bf16x8 kfa[2][2];
#pragma unroll
            for (int k2 = 0; k2 < 2; k2++)
#pragma unroll
                for (int h = 0; h < 2; h++)
                    kfa[k2][h] = *reinterpret_cast<const bf16x8*>(
                        (const char*)lds + ((kh * 2 + k2) * 16 + lo) * 128 + ((h * 64 + hi * 16) ^ ((lo & 7) << 4)));
            __builtin_amdgcn_s_setprio(1);
#pragma unroll
            for (int k2 = 0; k2 < 2; k2++) {
                f32x4 a2 = (f32x4){0.f, 0.f, 0.f, 0.f};
#pragma unroll
                for (int h = 0; h < 2; h++)
                    a2 = __builtin_amdgcn_mfma_f32_16x16x32_bf16(kfa[k2][h], qf[h], a2, 0, 0, 0);
                s[kh * 2 + k2] = a2;
            }
            __builtin_amdgcn_s_setprio(0);
        }
        if (j == qt) {                       // diagonal: causal mask (local indices)
            const int ql = wid * 16 + lo;
#pragma unroll
            for (int kt = 0; kt < 4; kt++)
#pragma unroll
                for (int r = 0; r < 4; r++)
                    if (kt * 16 + hi * 4 + r > ql) s[kt][r] = -1.0e30f;
        }
        // online softmax in log2 domain (Q pre-scaled), defer-max THR=8
        float vm = s[0][0];
#pragma unroll
        for (int kt = 0; kt < 4; kt++)
#pragma unroll
            for (int r = 0; r < 4; r++) vm = fmaxf(vm, s[kt][r]);
        vm = fmaxf(vm, __shfl_xor(vm, 16));
        vm = fmaxf(vm, __shfl_xor(vm, 32));
        if (!__all(vm <= m_run + 8.0f)) {
            float nm = fmaxf(m_run, vm);
            float sc = exp2f(m_run - nm);
            m_run = nm;
            l_part *= sc;
#pragma unroll
            for (int dt = 0; dt < 4; dt++)
#pragma unroll
                for (int r = 0; r < 4; r++) acc[dt][r] *= sc;   // cols=q=lo: lane-local
        }
        float ps = 0.f;
#pragma unroll
        for (int kt = 0; kt < 4; kt++)
#pragma unroll
            for (int r = 0; r < 4; r++) {
                float p = exp2f(s[kt][r] - m_run);
                s[kt][r] = p;
                ps += p;
            }
        l_part += ps;
        // pack P into PV B-fragments (kappa: e<4 -> kv=4hi+e; e>=4 -> 16+4hi+(e-4))
        bf16x8 pa[2];
        {
            union { u16 uu[8]; bf16x8 v; } q0, q1;
#pragma unroll
            for (int e = 0; e < 4; e++) {
                q0.uu[e]     = f2bf(s[0][e]);
                q0.uu[4 + e] = f2bf(s[1][e]);
                q1.uu[e]     = f2bf(s[2][e]);
                q1.uu[4 + e] = f2bf(s[3][e]);
            }
            pa[0] = q0.v;
            pa[1] = q1.v;
        }

        // PV swapped: acc[dt] = mfma(A=V^T frag, B=P) -> C[row=d][col=q=lo]
        const unsigned vtb = ldsb + 8192u + (unsigned)((hi * 64 + lo * 4) * 2);
#pragma unroll
        for (int pr = 0; pr < 2; pr++) {
            u32x2 tv[2][2][2];
#pragma unroll
            for (int d2 = 0; d2 < 2; d2++)
#pragma unroll
                for (int h = 0; h < 2; h++)
#pragma unroll
                    for (int sel = 0; sel < 2; sel++)
                        tv[d2][h][sel] = tr16(vtb + (unsigned)(((h * 4 + pr * 2 + d2) * 512 + sel * 256) * 2));
            asm volatile("s_waitcnt lgkmcnt(0)" ::: "memory");
            __builtin_amdgcn_sched_barrier(0);
            __builtin_amdgcn_s_setprio(1);
#pragma unroll
            for (int d2 = 0; d2 < 2; d2++) {
#pragma unroll
                for (int h = 0; h < 2; h++) {
                    union { unsigned int w[4]; bf16x8 v; } bv;
                    bv.w[0] = tv[d2][h][0][0];
                    bv.w[1] = tv[d2][h][0][1];
                    bv.w[2] = tv[d2][h][1][0];
                    bv.w[3] = tv[d2][h][1][1];
                    acc[pr * 2 + d2] = __builtin_amdgcn_mfma_f32_16x16x32_bf16(bv.v, pa[h], acc[pr * 2 + d2], 0, 0, 0);
                }
            }
            __builtin_amdgcn_s_setprio(0);
        }

        __syncthreads();    // all waves done reading tile j
        if (pf) {           // land prefetched tile j+1 (vmcnt wait ~free by now)
            *reinterpret_cast<uint4*>((char*)lds + dKb[0]) = pk0;
            *reinterpret_cast<uint4*>((char*)lds + dKb[1]) = pk1;
            *reinterpret_cast<uint4*>((char*)lds + dVb[0]) = pv0;
            *reinterpret_cast<uint4*>((char*)lds + dVb[1]) = pv1;
        }
    }

    // epilogue: finish l across lane groups (rows of same q), direct stores
    float l = l_part;
    l += __shfl_xor(l, 16);
    l += __shfl_xor(l, 32);
    const float inv = 1.0f / l;
    const int b = bh >> 4, hh = bh & 15;
    const size_t orow = ((size_t)(b * SEQ + qbase + lo)) * 1024 + hh * 64;
#pragma unroll
    for (int dt = 0; dt < 4; dt++) {
        union { u16 uu[4]; uint2 d2; } pk;
#pragma unroll
        for (int r = 0; r < 4; r++) pk.uu[r] = f2bf(acc[dt][r] * inv);
        *reinterpret_cast<uint2*>(O + orow + dt * 16 + hi * 4) = pk.d2;
    }
}

extern "C" void kernel_launch(void* const* d_in, const int* in_sizes, int n_in,
                              void* d_out, int out_size, void* d_ws, size_t ws_size,
                              hipStream_t stream) {
    const float* x  = (const float*)d_in[0];
    const float* Wq = (const float*)d_in[1];
    const float* Wk = (const float*)d_in[2];
    const float* Wv = (const float*)d_in[3];
    const float* Wo = (const float*)d_in[4];
    const float* bo = (const float*)d_in[5];
    float* out = (float*)d_out;

    char* ws = (char*)d_ws;
    u16* xb  = (u16*)ws;                              // 16 MiB, then weights contiguous
    u16* wqb = (u16*)(ws + 16777216);
    u16* wkb = wqb + 1048576;
    u16* wvb = wkb + 1048576;
    u16* wob = wvb + 1048576;
    u16* q   = (u16*)(ws + 16777216 + 8388608);       // [B][H][N][D] bf16
    u16* k   = q + 8388608;
    u16* v   = k + 8388608;
    u16* ao  = v + 8388608;                           // [B][N][H*64] bf16

    castk_all<<<3072, 256, 0, stream>>>(x, Wq, Wk, Wv, Wo, xb);

    gemm_qkv<<<dim3(ROWS / BM, 24), 256, 0, stream>>>(xb, wqb, wkb, wvb, q, k, v);

    attn<<<2048, 256, 0, stream>>>(q, k, v, ao);

    gemm_out<<<dim3(ROWS / BM, MODEL_DIM / BN), 256, 0, stream>>>(ao, wob, out, bo);
}

// Round 9
// 254.768 us; speedup vs baseline: 1.7481x; 1.7481x over previous
//
#include <hip/hip_runtime.h>
#include <hip/hip_bf16.h>

typedef unsigned short u16;
typedef __attribute__((ext_vector_type(8))) __bf16 bf16x8;
typedef __attribute__((ext_vector_type(4))) float f32x4;
typedef __attribute__((ext_vector_type(2))) unsigned int u32x2;

#define MODEL_DIM 1024
#define NUM_HEADS 16
#define HEAD_DIM  64
#define BATCH     4
#define SEQ       2048
#define ROWS      (BATCH*SEQ)     // 8192

static __device__ __forceinline__ u16 f2bf(float f) {
    union { __hip_bfloat16 h; u16 u; } cv;
    cv.h = __float2bfloat16(f);
    return cv.u;
}

static __device__ __forceinline__ void gload16(const u16* g, unsigned lds_byte) {
    __builtin_amdgcn_global_load_lds(
        (const __attribute__((address_space(1))) unsigned int*)g,
        (__attribute__((address_space(3))) unsigned int*)(uintptr_t)lds_byte,
        16, 0, 0);
}

// ---------------- fused cast f32 -> bf16 (x + 4 weights, contiguous out) ----
__global__ void castk_all(const float* __restrict__ x,
                          const float* __restrict__ w0, const float* __restrict__ w1,
                          const float* __restrict__ w2, const float* __restrict__ w3,
                          u16* __restrict__ out) {
    const int total = ROWS * MODEL_DIM + 4 * MODEL_DIM * MODEL_DIM;  // 12.58M
    int i = (blockIdx.x * blockDim.x + threadIdx.x) * 4;
    int stride = gridDim.x * blockDim.x * 4;
    for (; i < total; i += stride) {
        const float* src;
        int off;
        if (i < ROWS * MODEL_DIM) { src = x; off = i; }
        else {
            int j = i - ROWS * MODEL_DIM;
            int w = j >> 20;
            off = j & 1048575;
            src = (w == 0) ? w0 : (w == 1) ? w1 : (w == 2) ? w2 : w3;
        }
        float4 v = *reinterpret_cast<const float4*>(src + off);
        ushort4 o;
        o.x = f2bf(v.x); o.y = f2bf(v.y); o.z = f2bf(v.z); o.w = f2bf(v.w);
        *reinterpret_cast<ushort4*>(out + i) = o;
    }
}

// ---------------- NT GEMM core (gload_lds + XOR-swizzle staging) ----------
#define BM 128
#define BN 128
#define BK 64

static __device__ __forceinline__ void stage_tile(const u16* gbase, int K,
                                                  unsigned lds_byte_base, int t) {
#pragma unroll
    for (int ti = 0; ti < 4; ti++) {
        int o    = t * 8 + ti * 2048;
        int row  = o >> 6;
        int colb = ((o & 63) * 2) ^ ((row & 7) << 4);
        gload16(gbase + (size_t)row * K + (colb >> 1), lds_byte_base + o * 2);
    }
}

static __device__ __forceinline__ bf16x8 frag_read(const char* base, int row, int h,
                                                   int lo, int hi) {
    return *reinterpret_cast<const bf16x8*>(
        base + row * 128 + ((h * 64 + hi * 16) ^ ((lo & 7) << 4)));
}

// fused QKV projection: grid (M/128, 24); Q pre-scaled by 0.125*log2(e)
__global__ __launch_bounds__(256) void gemm_qkv(
    const u16* __restrict__ A,
    const u16* __restrict__ Wq, const u16* __restrict__ Wk, const u16* __restrict__ Wv,
    u16* __restrict__ qO, u16* __restrict__ kO, u16* __restrict__ vO)
{
    __shared__ u16 As[BM * BK];
    __shared__ u16 Bs[BN * BK];
    const int t    = threadIdx.x;
    const int wid  = t >> 6;
    const int lane = t & 63;
    const int lo   = lane & 15, hi = lane >> 4;
    const int bm   = blockIdx.x * BM;
    const int mat  = blockIdx.y >> 3;
    const int bn   = (blockIdx.y & 7) * BN;
    const u16* W   = (mat == 0) ? Wq : (mat == 1) ? Wk : Wv;
    u16* outB      = (mat == 0) ? qO : (mat == 1) ? kO : vO;
    const float qscale = (mat == 0) ? 0.18033688f : 1.0f;   // 0.125*log2(e)
    const int wr   = wid >> 1, wc = wid & 1;
    const int K = MODEL_DIM;
    const unsigned AsB = (unsigned)(uintptr_t)As;
    const unsigned BsB = (unsigned)(uintptr_t)Bs;

    f32x4 acc[4][4];
#pragma unroll
    for (int m = 0; m < 4; m++)
#pragma unroll
        for (int n = 0; n < 4; n++) acc[m][n] = (f32x4){0.f, 0.f, 0.f, 0.f};

    for (int k0 = 0; k0 < K; k0 += BK) {
        __syncthreads();
        stage_tile(A + (size_t)bm * K + k0, K, AsB, t);
        stage_tile(W + (size_t)bn * K + k0, K, BsB, t);
        __syncthreads();
#pragma unroll
        for (int h = 0; h < 2; h++) {
            bf16x8 af[4], bfr[4];
#pragma unroll
            for (int m = 0; m < 4; m++)
                af[m] = frag_read((const char*)As, wr * 64 + m * 16 + lo, h, lo, hi);
#pragma unroll
            for (int n = 0; n < 4; n++)
                bfr[n] = frag_read((const char*)Bs, wc * 64 + n * 16 + lo, h, lo, hi);
#pragma unroll
            for (int m = 0; m < 4; m++)
#pragma unroll
                for (int n = 0; n < 4; n++)
                    acc[m][n] = __builtin_amdgcn_mfma_f32_16x16x32_bf16(af[m], bfr[n], acc[m][n], 0, 0, 0);
        }
    }

#pragma unroll
    for (int m = 0; m < 4; m++)
#pragma unroll
        for (int n = 0; n < 4; n++)
#pragma unroll
            for (int r = 0; r < 4; r++) {
                int row = bm + wr * 64 + m * 16 + hi * 4 + r;
                int col = bn + wc * 64 + n * 16 + lo;
                int b = row >> 11, np = row & 2047;
                int hh = col >> 6, dd = col & 63;
                outB[(((size_t)(b * NUM_HEADS + hh) * SEQ + np) << 6) + dd] = f2bf(acc[m][n][r] * qscale);
            }
}

// out-projection: C = A * Wo^T + bias, f32 out
__global__ __launch_bounds__(256) void gemm_out(
    const u16* __restrict__ A,
    const u16* __restrict__ W,
    float* __restrict__ outF,
    const float* __restrict__ bias)
{
    __shared__ u16 As[BM * BK];
    __shared__ u16 Bs[BN * BK];
    const int t    = threadIdx.x;
    const int wid  = t >> 6;
    const int lane = t & 63;
    const int lo   = lane & 15, hi = lane >> 4;
    const int bm   = blockIdx.x * BM;
    const int bn   = blockIdx.y * BN;
    const int wr   = wid >> 1, wc = wid & 1;
    const int K = MODEL_DIM, N = MODEL_DIM;
    const unsigned AsB = (unsigned)(uintptr_t)As;
    const unsigned BsB = (unsigned)(uintptr_t)Bs;

    f32x4 acc[4][4];
#pragma unroll
    for (int m = 0; m < 4; m++)
#pragma unroll
        for (int n = 0; n < 4; n++) acc[m][n] = (f32x4){0.f, 0.f, 0.f, 0.f};

    for (int k0 = 0; k0 < K; k0 += BK) {
        __syncthreads();
        stage_tile(A + (size_t)bm * K + k0, K, AsB, t);
        stage_tile(W + (size_t)bn * K + k0, K, BsB, t);
        __syncthreads();
#pragma unroll
        for (int h = 0; h < 2; h++) {
            bf16x8 af[4], bfr[4];
#pragma unroll
            for (int m = 0; m < 4; m++)
                af[m] = frag_read((const char*)As, wr * 64 + m * 16 + lo, h, lo, hi);
#pragma unroll
            for (int n = 0; n < 4; n++)
                bfr[n] = frag_read((const char*)Bs, wc * 64 + n * 16 + lo, h, lo, hi);
#pragma unroll
            for (int m = 0; m < 4; m++)
#pragma unroll
                for (int n = 0; n < 4; n++)
                    acc[m][n] = __builtin_amdgcn_mfma_f32_16x16x32_bf16(af[m], bfr[n], acc[m][n], 0, 0, 0);
        }
    }

#pragma unroll
    for (int m = 0; m < 4; m++)
#pragma unroll
        for (int n = 0; n < 4; n++)
#pragma unroll
            for (int r = 0; r < 4; r++) {
                int row = bm + wr * 64 + m * 16 + hi * 4 + r;
                int col = bn + wc * 64 + n * 16 + lo;
                outF[(size_t)row * N + col] = acc[m][n][r] + bias[col];
            }
}

// ---------------- flash attention v8 -------------------------------------
// Equal-length blocks: 512 threads (8 waves), block owns q-tile pair
// (bh, p) and (bh, 31-p). Per tile: wave-group 0 = even KV tiles, group 1 =
// odd; 2 KV tiles staged per round (32KB LDS); group partials merged in LDS.
// Every block runs exactly 17 rounds -> no drain tail. Inner compute = v6.

static __device__ __forceinline__ u32x2 tr16(unsigned int addr) {
    u32x2 r;
    asm volatile("ds_read_b64_tr_b16 %0, %1" : "=v"(r) : "v"(addr));
    return r;
}

__global__ __launch_bounds__(512, 8) void attn(
    const u16* __restrict__ Q,   // [B*H][N][64]
    const u16* __restrict__ Kg,
    const u16* __restrict__ Vg,
    u16* __restrict__ O)         // [B][N][H*64]
{
    // LDS bytes: K0 @0, K1 @8192, V0 @16384, V1 @24576 (32KB).
    // Merge area (post-compute) reuses @0..18KB.
    __shared__ u16 lds[16384];
    const int t    = threadIdx.x;
    const int wv   = t >> 6, lane = t & 63;
    const int grp  = wv >> 2;                 // 0: even j, 1: odd j
    const int lo   = lane & 15, hi = lane >> 4;

    const int g    = blockIdx.x;              // 0..1023
    const int slot = g & 255;
    const int k4   = g >> 8;                  // 0..3
    const int xcd  = slot >> 5;
    const int cx   = slot & 31;
    const int bh   = xcd * 8 + (cx & 7);      // head-batch pinned to one XCD
    const int p    = (cx >> 3) + 4 * k4;      // 0..15 pair index

    const size_t base = (size_t)bh * SEQ * 64;
    const unsigned ldsb = (unsigned)(uintptr_t)lds;

    // staging: one 16B load per tile per thread (512 thr x 16B = 8KB tile)
    int sK, sV;
    {
        int o    = t * 8;
        int row  = o >> 6;
        int colb = ((o & 63) * 2) ^ ((row & 7) << 4);
        sK = row * 64 + (colb >> 1);
        int st = o >> 9;
        int kv = (st >> 2) * 32 + ((o >> 4) & 31);
        int d  = (st & 3) * 16 + (o & 15);
        sV = kv * 64 + d;
    }
    const unsigned dst = (unsigned)(t * 16);

    const int b_out = bh >> 4, hh = bh & 15;

#pragma unroll 1
    for (int tile = 0; tile < 2; tile++) {
        const int qt    = tile ? (31 - p) : p;
        const int qbase = qt * 64 + (wv & 3) * 16;

        // Q fragments (B-operand): lane holds Q[qbase+lo][h*32+hi*8+..]
        bf16x8 qf[2];
#pragma unroll
        for (int h = 0; h < 2; h++)
            qf[h] = *reinterpret_cast<const bf16x8*>(Q + base + (size_t)(qbase + lo) * 64 + h * 32 + hi * 8);
        asm volatile("" : "+v"(qf[0]), "+v"(qf[1]));

        float m_run = -3.0e38f, l_part = 0.f;
        f32x4 acc[4];
#pragma unroll
        for (int dt = 0; dt < 4; dt++) acc[dt] = (f32x4){0.f, 0.f, 0.f, 0.f};

        const int R = (qt + 2) >> 1;          // ceil((qt+1)/2)
        for (int r = 0; r < R; r++) {
            __syncthreads();                  // prev round's readers done
            {
                const u16* Kt = Kg + base + (size_t)(2 * r) * 4096;
                const u16* Vt = Vg + base + (size_t)(2 * r) * 4096;
                gload16(Kt + sK, ldsb + dst);
                gload16(Vt + sV, ldsb + 16384u + dst);
                if (2 * r + 1 <= qt) {        // block-uniform
                    gload16(Kt + 4096 + sK, ldsb + 8192u + dst);
                    gload16(Vt + 4096 + sV, ldsb + 24576u + dst);
                }
            }
            asm volatile("s_waitcnt vmcnt(0)" ::: "memory");
            __builtin_amdgcn_s_barrier();
            __builtin_amdgcn_sched_barrier(0);

            const int jw = 2 * r + grp;
            if (jw <= qt) {
                const char* Kbase = (const char*)lds + grp * 8192;
                // S^T = K Q^T: lane holds S[q=qbase+lo][kv=jw*64+kt*16+hi*4+r]
                f32x4 s[4];
#pragma unroll
                for (int kh = 0; kh < 2; kh++) {
                    bf16x8 kfa[2][2];
#pragma unroll
                    for (int k2 = 0; k2 < 2; k2++)
#pragma unroll
                        for (int h = 0; h < 2; h++)
                            kfa[k2][h] = *reinterpret_cast<const bf16x8*>(
                                Kbase + ((kh * 2 + k2) * 16 + lo) * 128 + ((h * 64 + hi * 16) ^ ((lo & 7) << 4)));
                    __builtin_amdgcn_s_setprio(1);
#pragma unroll
                    for (int k2 = 0; k2 < 2; k2++) {
                        f32x4 a2 = (f32x4){0.f, 0.f, 0.f, 0.f};
#pragma unroll
                        for (int h = 0; h < 2; h++)
                            a2 = __builtin_amdgcn_mfma_f32_16x16x32_bf16(kfa[k2][h], qf[h], a2, 0, 0, 0);
                        s[kh * 2 + k2] = a2;
                    }
                    __builtin_amdgcn_s_setprio(0);
                }
                if (jw == qt) {               // diagonal: causal mask
                    const int ql = (wv & 3) * 16 + lo;
#pragma unroll
                    for (int kt = 0; kt < 4; kt++)
#pragma unroll
                        for (int rr = 0; rr < 4; rr++)
                            if (kt * 16 + hi * 4 + rr > ql) s[kt][rr] = -1.0e30f;
                }
                // online softmax (log2 domain, Q pre-scaled), defer-max THR=8
                float vm = s[0][0];
#pragma unroll
                for (int kt = 0; kt < 4; kt++)
#pragma unroll
                    for (int rr = 0; rr < 4; rr++) vm = fmaxf(vm, s[kt][rr]);
                vm = fmaxf(vm, __shfl_xor(vm, 16));
                vm = fmaxf(vm, __shfl_xor(vm, 32));
                if (!__all(vm <= m_run + 8.0f)) {
                    float nm = fmaxf(m_run, vm);
                    float sc = exp2f(m_run - nm);
                    m_run = nm;
                    l_part *= sc;
#pragma unroll
                    for (int dt = 0; dt < 4; dt++)
#pragma unroll
                        for (int rr = 0; rr < 4; rr++) acc[dt][rr] *= sc;
                }
                float ps = 0.f;
#pragma unroll
                for (int kt = 0; kt < 4; kt++)
#pragma unroll
                    for (int rr = 0; rr < 4; rr++) {
                        float pv = exp2f(s[kt][rr] - m_run);
                        s[kt][rr] = pv;
                        ps += pv;
                    }
                l_part += ps;
                bf16x8 pa[2];
                {
                    union { u16 uu[8]; bf16x8 v; } q0, q1;
#pragma unroll
                    for (int e = 0; e < 4; e++) {
                        q0.uu[e]     = f2bf(s[0][e]);
                        q0.uu[4 + e] = f2bf(s[1][e]);
                        q1.uu[e]     = f2bf(s[2][e]);
                        q1.uu[4 + e] = f2bf(s[3][e]);
                    }
                    pa[0] = q0.v;
                    pa[1] = q1.v;
                }
                // PV swapped: acc[dt] = mfma(A=V^T frag, B=P) -> C[row=d][col=q=lo]
                const unsigned vtb = ldsb + 16384u + (unsigned)(grp * 8192) + (unsigned)((hi * 64 + lo * 4) * 2);
#pragma unroll
                for (int pr = 0; pr < 2; pr++) {
                    u32x2 tv[2][2][2];
#pragma unroll
                    for (int d2 = 0; d2 < 2; d2++)
#pragma unroll
                        for (int h = 0; h < 2; h++)
#pragma unroll
                            for (int sel = 0; sel < 2; sel++)
                                tv[d2][h][sel] = tr16(vtb + (unsigned)(((h * 4 + pr * 2 + d2) * 512 + sel * 256) * 2));
                    asm volatile("s_waitcnt lgkmcnt(0)" ::: "memory");
                    __builtin_amdgcn_sched_barrier(0);
                    __builtin_amdgcn_s_setprio(1);
#pragma unroll
                    for (int d2 = 0; d2 < 2; d2++) {
#pragma unroll
                        for (int h = 0; h < 2; h++) {
                            union { unsigned int w[4]; bf16x8 v; } bv;
                            bv.w[0] = tv[d2][h][0][0];
                            bv.w[1] = tv[d2][h][0][1];
                            bv.w[2] = tv[d2][h][1][0];
                            bv.w[3] = tv[d2][h][1][1];
                            acc[pr * 2 + d2] = __builtin_amdgcn_mfma_f32_16x16x32_bf16(bv.v, pa[h], acc[pr * 2 + d2], 0, 0, 0);
                        }
                    }
                    __builtin_amdgcn_s_setprio(0);
                }
            }
        }

        // merge group partials in LDS, group 0 writes O
        __syncthreads();                      // all compute done; KV dead
        float* ms = (float*)((char*)lds + (wv & 3) * 4608 + lane * 72);
        if (grp == 1) {
#pragma unroll
            for (int dt = 0; dt < 4; dt++)
#pragma unroll
                for (int rr = 0; rr < 4; rr++) ms[dt * 4 + rr] = acc[dt][rr];
            ms[16] = m_run;
            ms[17] = l_part;
        }
        __syncthreads();
        if (grp == 0) {
            float m2 = ms[16], l2 = ms[17];
            float mm = fmaxf(m_run, m2);
            float sc1 = exp2f(m_run - mm);
            float sc2 = exp2f(m2 - mm);
            float l = l_part * sc1 + l2 * sc2;
            l += __shfl_xor(l, 16);
            l += __shfl_xor(l, 32);
            const float inv = 1.0f / l;
            const size_t orow = ((size_t)(b_out * SEQ + qbase + lo)) * 1024 + hh * 64;
#pragma unroll
            for (int dt = 0; dt < 4; dt++) {
                union { u16 uu[4]; uint2 d2; } pk;
#pragma unroll
                for (int rr = 0; rr < 4; rr++)
                    pk.uu[rr] = f2bf((acc[dt][rr] * sc1 + ms[dt * 4 + rr] * sc2) * inv);
                *reinterpret_cast<uint2*>(O + orow + dt * 16 + hi * 4) = pk.d2;
            }
        }
    }
}

extern "C" void kernel_launch(void* const* d_in, const int* in_sizes, int n_in,
                              void* d_out, int out_size, void* d_ws, size_t ws_size,
                              hipStream_t stream) {
    const float* x  = (const float*)d_in[0];
    const float* Wq = (const float*)d_in[1];
    const float* Wk = (const float*)d_in[2];
    const float* Wv = (const float*)d_in[3];
    const float* Wo = (const float*)d_in[4];
    const float* bo = (const float*)d_in[5];
    float* out = (float*)d_out;

    char* ws = (char*)d_ws;
    u16* xb  = (u16*)ws;                              // 16 MiB, then weights contiguous
    u16* wqb = (u16*)(ws + 16777216);
    u16* wkb = wqb + 1048576;
    u16* wvb = wkb + 1048576;
    u16* wob = wvb + 1048576;
    u16* q   = (u16*)(ws + 16777216 + 8388608);       // [B][H][N][D] bf16
    u16* k   = q + 8388608;
    u16* v   = k + 8388608;
    u16* ao  = v + 8388608;                           // [B][N][H*64] bf16

    castk_all<<<3072, 256, 0, stream>>>(x, Wq, Wk, Wv, Wo, xb);

    gemm_qkv<<<dim3(ROWS / BM, 24), 256, 0, stream>>>(xb, wqb, wkb, wvb, q, k, v);

    attn<<<1024, 512, 0, stream>>>(q, k, v, ao);

    gemm_out<<<dim3(ROWS / BM, MODEL_DIM / BN), 256, 0, stream>>>(ao, wob, out, bo);
}

// Round 10
// 237.229 us; speedup vs baseline: 1.8773x; 1.0739x over previous
//
#include <hip/hip_runtime.h>
#include <hip/hip_bf16.h>

typedef unsigned short u16;
typedef __attribute__((ext_vector_type(8))) __bf16 bf16x8;
typedef __attribute__((ext_vector_type(4))) float f32x4;
typedef __attribute__((ext_vector_type(2))) unsigned int u32x2;

#define MODEL_DIM 1024
#define NUM_HEADS 16
#define HEAD_DIM  64
#define BATCH     4
#define SEQ       2048
#define ROWS      (BATCH*SEQ)     // 8192

static __device__ __forceinline__ u16 f2bf(float f) {
    union { __hip_bfloat16 h; u16 u; } cv;
    cv.h = __float2bfloat16(f);
    return cv.u;
}

static __device__ __forceinline__ void gload16(const u16* g, unsigned lds_byte) {
    __builtin_amdgcn_global_load_lds(
        (const __attribute__((address_space(1))) unsigned int*)g,
        (__attribute__((address_space(3))) unsigned int*)(uintptr_t)lds_byte,
        16, 0, 0);
}

// ---------------- fused cast f32 -> bf16 (x + 4 weights, contiguous out) ----
__global__ void castk_all(const float* __restrict__ x,
                          const float* __restrict__ w0, const float* __restrict__ w1,
                          const float* __restrict__ w2, const float* __restrict__ w3,
                          u16* __restrict__ out) {
    const int total = ROWS * MODEL_DIM + 4 * MODEL_DIM * MODEL_DIM;  // 12.58M
    int i = (blockIdx.x * blockDim.x + threadIdx.x) * 4;
    int stride = gridDim.x * blockDim.x * 4;
    for (; i < total; i += stride) {
        const float* src;
        int off;
        if (i < ROWS * MODEL_DIM) { src = x; off = i; }
        else {
            int j = i - ROWS * MODEL_DIM;
            int w = j >> 20;
            off = j & 1048575;
            src = (w == 0) ? w0 : (w == 1) ? w1 : (w == 2) ? w2 : w3;
        }
        float4 v = *reinterpret_cast<const float4*>(src + off);
        ushort4 o;
        o.x = f2bf(v.x); o.y = f2bf(v.y); o.z = f2bf(v.z); o.w = f2bf(v.w);
        *reinterpret_cast<ushort4*>(out + i) = o;
    }
}

// ---------------- NT GEMM core (gload_lds + XOR-swizzle staging) ----------
#define BM 128
#define BN 128
#define BK 64

static __device__ __forceinline__ void stage_tile(const u16* gbase, int K,
                                                  unsigned lds_byte_base, int t) {
#pragma unroll
    for (int ti = 0; ti < 4; ti++) {
        int o    = t * 8 + ti * 2048;
        int row  = o >> 6;
        int colb = ((o & 63) * 2) ^ ((row & 7) << 4);
        gload16(gbase + (size_t)row * K + (colb >> 1), lds_byte_base + o * 2);
    }
}

static __device__ __forceinline__ bf16x8 frag_read(const char* base, int row, int h,
                                                   int lo, int hi) {
    return *reinterpret_cast<const bf16x8*>(
        base + row * 128 + ((h * 64 + hi * 16) ^ ((lo & 7) << 4)));
}

// fused QKV projection: grid (M/128, 24); Q pre-scaled by 0.125*log2(e)
__global__ __launch_bounds__(256) void gemm_qkv(
    const u16* __restrict__ A,
    const u16* __restrict__ Wq, const u16* __restrict__ Wk, const u16* __restrict__ Wv,
    u16* __restrict__ qO, u16* __restrict__ kO, u16* __restrict__ vO)
{
    __shared__ u16 As[BM * BK];
    __shared__ u16 Bs[BN * BK];
    const int t    = threadIdx.x;
    const int wid  = t >> 6;
    const int lane = t & 63;
    const int lo   = lane & 15, hi = lane >> 4;
    const int bm   = blockIdx.x * BM;
    const int mat  = blockIdx.y >> 3;
    const int bn   = (blockIdx.y & 7) * BN;
    const u16* W   = (mat == 0) ? Wq : (mat == 1) ? Wk : Wv;
    u16* outB      = (mat == 0) ? qO : (mat == 1) ? kO : vO;
    const float qscale = (mat == 0) ? 0.18033688f : 1.0f;   // 0.125*log2(e)
    const int wr   = wid >> 1, wc = wid & 1;
    const int K = MODEL_DIM;
    const unsigned AsB = (unsigned)(uintptr_t)As;
    const unsigned BsB = (unsigned)(uintptr_t)Bs;

    f32x4 acc[4][4];
#pragma unroll
    for (int m = 0; m < 4; m++)
#pragma unroll
        for (int n = 0; n < 4; n++) acc[m][n] = (f32x4){0.f, 0.f, 0.f, 0.f};

    for (int k0 = 0; k0 < K; k0 += BK) {
        __syncthreads();
        stage_tile(A + (size_t)bm * K + k0, K, AsB, t);
        stage_tile(W + (size_t)bn * K + k0, K, BsB, t);
        __syncthreads();
#pragma unroll
        for (int h = 0; h < 2; h++) {
            bf16x8 af[4], bfr[4];
#pragma unroll
            for (int m = 0; m < 4; m++)
                af[m] = frag_read((const char*)As, wr * 64 + m * 16 + lo, h, lo, hi);
#pragma unroll
            for (int n = 0; n < 4; n++)
                bfr[n] = frag_read((const char*)Bs, wc * 64 + n * 16 + lo, h, lo, hi);
#pragma unroll
            for (int m = 0; m < 4; m++)
#pragma unroll
                for (int n = 0; n < 4; n++)
                    acc[m][n] = __builtin_amdgcn_mfma_f32_16x16x32_bf16(af[m], bfr[n], acc[m][n], 0, 0, 0);
        }
    }

#pragma unroll
    for (int m = 0; m < 4; m++)
#pragma unroll
        for (int n = 0; n < 4; n++)
#pragma unroll
            for (int r = 0; r < 4; r++) {
                int row = bm + wr * 64 + m * 16 + hi * 4 + r;
                int col = bn + wc * 64 + n * 16 + lo;
                int b = row >> 11, np = row & 2047;
                int hh = col >> 6, dd = col & 63;
                outB[(((size_t)(b * NUM_HEADS + hh) * SEQ + np) << 6) + dd] = f2bf(acc[m][n][r] * qscale);
            }
}

// out-projection: C = A * Wo^T + bias, f32 out
__global__ __launch_bounds__(256) void gemm_out(
    const u16* __restrict__ A,
    const u16* __restrict__ W,
    float* __restrict__ outF,
    const float* __restrict__ bias)
{
    __shared__ u16 As[BM * BK];
    __shared__ u16 Bs[BN * BK];
    const int t    = threadIdx.x;
    const int wid  = t >> 6;
    const int lane = t & 63;
    const int lo   = lane & 15, hi = lane >> 4;
    const int bm   = blockIdx.x * BM;
    const int bn   = blockIdx.y * BN;
    const int wr   = wid >> 1, wc = wid & 1;
    const int K = MODEL_DIM, N = MODEL_DIM;
    const unsigned AsB = (unsigned)(uintptr_t)As;
    const unsigned BsB = (unsigned)(uintptr_t)Bs;

    f32x4 acc[4][4];
#pragma unroll
    for (int m = 0; m < 4; m++)
#pragma unroll
        for (int n = 0; n < 4; n++) acc[m][n] = (f32x4){0.f, 0.f, 0.f, 0.f};

    for (int k0 = 0; k0 < K; k0 += BK) {
        __syncthreads();
        stage_tile(A + (size_t)bm * K + k0, K, AsB, t);
        stage_tile(W + (size_t)bn * K + k0, K, BsB, t);
        __syncthreads();
#pragma unroll
        for (int h = 0; h < 2; h++) {
            bf16x8 af[4], bfr[4];
#pragma unroll
            for (int m = 0; m < 4; m++)
                af[m] = frag_read((const char*)As, wr * 64 + m * 16 + lo, h, lo, hi);
#pragma unroll
            for (int n = 0; n < 4; n++)
                bfr[n] = frag_read((const char*)Bs, wc * 64 + n * 16 + lo, h, lo, hi);
#pragma unroll
            for (int m = 0; m < 4; m++)
#pragma unroll
                for (int n = 0; n < 4; n++)
                    acc[m][n] = __builtin_amdgcn_mfma_f32_16x16x32_bf16(af[m], bfr[n], acc[m][n], 0, 0, 0);
        }
    }

#pragma unroll
    for (int m = 0; m < 4; m++)
#pragma unroll
        for (int n = 0; n < 4; n++)
#pragma unroll
            for (int r = 0; r < 4; r++) {
                int row = bm + wr * 64 + m * 16 + hi * 4 + r;
                int col = bn + wc * 64 + n * 16 + lo;
                outF[(size_t)row * N + col] = acc[m][n][r] + bias[col];
            }
}

// ---------------- flash attention v9 -------------------------------------
// v8 equal-length pair structure, register-peak reduced to kill the spill:
//  - QK: K fragments loaded per-kt (8 VGPR live) instead of 16
//  - PV: tr16 in 4 sections of 8 VGPR instead of 2 sections of 16
// Unified VGPR+AGPR budget at 8 waves/EU is 64/wave; peaks now ~56.

static __device__ __forceinline__ u32x2 tr16(unsigned int addr) {
    u32x2 r;
    asm volatile("ds_read_b64_tr_b16 %0, %1" : "=v"(r) : "v"(addr));
    return r;
}

__global__ __launch_bounds__(512, 8) void attn(
    const u16* __restrict__ Q,   // [B*H][N][64]
    const u16* __restrict__ Kg,
    const u16* __restrict__ Vg,
    u16* __restrict__ O)         // [B][N][H*64]
{
    // LDS bytes: K0 @0, K1 @8192, V0 @16384, V1 @24576 (32KB).
    __shared__ u16 lds[16384];
    const int t    = threadIdx.x;
    const int wv   = t >> 6, lane = t & 63;
    const int grp  = wv >> 2;                 // 0: even j, 1: odd j
    const int lo   = lane & 15, hi = lane >> 4;

    const int g    = blockIdx.x;              // 0..1023
    const int slot = g & 255;
    const int k4   = g >> 8;                  // 0..3
    const int xcd  = slot >> 5;
    const int cx   = slot & 31;
    const int bh   = xcd * 8 + (cx & 7);      // head-batch pinned to one XCD
    const int p    = (cx >> 3) + 4 * k4;      // 0..15 pair index

    const size_t base = (size_t)bh * SEQ * 64;
    const unsigned ldsb = (unsigned)(uintptr_t)lds;

    // staging: one 16B load per tile per thread (512 thr x 16B = 8KB tile)
    int sK, sV;
    {
        int o    = t * 8;
        int row  = o >> 6;
        int colb = ((o & 63) * 2) ^ ((row & 7) << 4);
        sK = row * 64 + (colb >> 1);
        int st = o >> 9;
        int kv = (st >> 2) * 32 + ((o >> 4) & 31);
        int d  = (st & 3) * 16 + (o & 15);
        sV = kv * 64 + d;
    }

    const int b_out = bh >> 4, hh = bh & 15;

#pragma unroll 1
    for (int tile = 0; tile < 2; tile++) {
        const int qt    = tile ? (31 - p) : p;
        const int qbase = qt * 64 + (wv & 3) * 16;

        // Q fragments (B-operand): lane holds Q[qbase+lo][h*32+hi*8+..]
        bf16x8 qf[2];
#pragma unroll
        for (int h = 0; h < 2; h++)
            qf[h] = *reinterpret_cast<const bf16x8*>(Q + base + (size_t)(qbase + lo) * 64 + h * 32 + hi * 8);
        asm volatile("" : "+v"(qf[0]), "+v"(qf[1]));

        float m_run = -3.0e38f, l_part = 0.f;
        f32x4 acc[4];
#pragma unroll
        for (int dt = 0; dt < 4; dt++) acc[dt] = (f32x4){0.f, 0.f, 0.f, 0.f};

        const int R = (qt + 2) >> 1;          // ceil((qt+1)/2)
        for (int r = 0; r < R; r++) {
            __syncthreads();                  // prev round's readers done
            {
                const u16* Kt = Kg + base + (size_t)(2 * r) * 4096;
                const u16* Vt = Vg + base + (size_t)(2 * r) * 4096;
                gload16(Kt + sK, ldsb + (unsigned)(t * 16));
                gload16(Vt + sV, ldsb + 16384u + (unsigned)(t * 16));
                if (2 * r + 1 <= qt) {        // block-uniform
                    gload16(Kt + 4096 + sK, ldsb + 8192u + (unsigned)(t * 16));
                    gload16(Vt + 4096 + sV, ldsb + 24576u + (unsigned)(t * 16));
                }
            }
            asm volatile("s_waitcnt vmcnt(0)" ::: "memory");
            __builtin_amdgcn_s_barrier();
            __builtin_amdgcn_sched_barrier(0);

            const int jw = 2 * r + grp;
            if (jw <= qt) {
                const char* Kbase = (const char*)lds + grp * 8192;
                // S^T = K Q^T, K frags loaded per-kt (low reg peak)
                f32x4 s[4];
#pragma unroll
                for (int kt = 0; kt < 4; kt++) {
                    bf16x8 kf0 = *reinterpret_cast<const bf16x8*>(
                        Kbase + (kt * 16 + lo) * 128 + ((hi * 16) ^ ((lo & 7) << 4)));
                    bf16x8 kf1 = *reinterpret_cast<const bf16x8*>(
                        Kbase + (kt * 16 + lo) * 128 + ((64 + hi * 16) ^ ((lo & 7) << 4)));
                    __builtin_amdgcn_s_setprio(1);
                    f32x4 a2 = (f32x4){0.f, 0.f, 0.f, 0.f};
                    a2 = __builtin_amdgcn_mfma_f32_16x16x32_bf16(kf0, qf[0], a2, 0, 0, 0);
                    a2 = __builtin_amdgcn_mfma_f32_16x16x32_bf16(kf1, qf[1], a2, 0, 0, 0);
                    __builtin_amdgcn_s_setprio(0);
                    s[kt] = a2;
                }
                if (jw == qt) {               // diagonal: causal mask
                    const int ql = (wv & 3) * 16 + lo;
#pragma unroll
                    for (int kt = 0; kt < 4; kt++)
#pragma unroll
                        for (int rr = 0; rr < 4; rr++)
                            if (kt * 16 + hi * 4 + rr > ql) s[kt][rr] = -1.0e30f;
                }
                // online softmax (log2 domain, Q pre-scaled), defer-max THR=8
                float vm = s[0][0];
#pragma unroll
                for (int kt = 0; kt < 4; kt++)
#pragma unroll
                    for (int rr = 0; rr < 4; rr++) vm = fmaxf(vm, s[kt][rr]);
                vm = fmaxf(vm, __shfl_xor(vm, 16));
                vm = fmaxf(vm, __shfl_xor(vm, 32));
                if (!__all(vm <= m_run + 8.0f)) {
                    float nm = fmaxf(m_run, vm);
                    float sc = exp2f(m_run - nm);
                    m_run = nm;
                    l_part *= sc;
#pragma unroll
                    for (int dt = 0; dt < 4; dt++)
#pragma unroll
                        for (int rr = 0; rr < 4; rr++) acc[dt][rr] *= sc;
                }
                float ps = 0.f;
#pragma unroll
                for (int kt = 0; kt < 4; kt++)
#pragma unroll
                    for (int rr = 0; rr < 4; rr++) {
                        float pv = exp2f(s[kt][rr] - m_run);
                        s[kt][rr] = pv;
                        ps += pv;
                    }
                l_part += ps;
                bf16x8 pa[2];
                {
                    union { u16 uu[8]; bf16x8 v; } q0, q1;
#pragma unroll
                    for (int e = 0; e < 4; e++) {
                        q0.uu[e]     = f2bf(s[0][e]);
                        q0.uu[4 + e] = f2bf(s[1][e]);
                        q1.uu[e]     = f2bf(s[2][e]);
                        q1.uu[4 + e] = f2bf(s[3][e]);
                    }
                    pa[0] = q0.v;
                    pa[1] = q1.v;
                }
                // PV swapped, 4 sections of {4 tr16 (8 VGPR), 2 MFMA}
                const unsigned vtb = ldsb + 16384u + (unsigned)(grp * 8192) + (unsigned)((hi * 64 + lo * 4) * 2);
#pragma unroll
                for (int dt = 0; dt < 4; dt++) {
                    u32x2 tv[2][2];           // [h][sel]
#pragma unroll
                    for (int h = 0; h < 2; h++)
#pragma unroll
                        for (int sel = 0; sel < 2; sel++)
                            tv[h][sel] = tr16(vtb + (unsigned)(((h * 4 + dt) * 512 + sel * 256) * 2));
                    asm volatile("s_waitcnt lgkmcnt(0)" ::: "memory");
                    __builtin_amdgcn_sched_barrier(0);
                    __builtin_amdgcn_s_setprio(1);
#pragma unroll
                    for (int h = 0; h < 2; h++) {
                        union { unsigned int w[4]; bf16x8 v; } bv;
                        bv.w[0] = tv[h][0][0];
                        bv.w[1] = tv[h][0][1];
                        bv.w[2] = tv[h][1][0];
                        bv.w[3] = tv[h][1][1];
                        acc[dt] = __builtin_amdgcn_mfma_f32_16x16x32_bf16(bv.v, pa[h], acc[dt], 0, 0, 0);
                    }
                    __builtin_amdgcn_s_setprio(0);
                }
            }
        }

        // merge group partials in LDS, group 0 writes O
        __syncthreads();                      // all compute done; KV dead
        float* ms = (float*)((char*)lds + (wv & 3) * 4608 + lane * 72);
        if (grp == 1) {
#pragma unroll
            for (int dt = 0; dt < 4; dt++)
#pragma unroll
                for (int rr = 0; rr < 4; rr++) ms[dt * 4 + rr] = acc[dt][rr];
            ms[16] = m_run;
            ms[17] = l_part;
        }
        __syncthreads();
        if (grp == 0) {
            float m2 = ms[16], l2 = ms[17];
            float mm = fmaxf(m_run, m2);
            float sc1 = exp2f(m_run - mm);
            float sc2 = exp2f(m2 - mm);
            float l = l_part * sc1 + l2 * sc2;
            l += __shfl_xor(l, 16);
            l += __shfl_xor(l, 32);
            const float inv = 1.0f / l;
            const size_t orow = ((size_t)(b_out * SEQ + qbase + lo)) * 1024 + hh * 64;
#pragma unroll
            for (int dt = 0; dt < 4; dt++) {
                union { u16 uu[4]; uint2 d2; } pk;
#pragma unroll
                for (int rr = 0; rr < 4; rr++)
                    pk.uu[rr] = f2bf((acc[dt][rr] * sc1 + ms[dt * 4 + rr] * sc2) * inv);
                *reinterpret_cast<uint2*>(O + orow + dt * 16 + hi * 4) = pk.d2;
            }
        }
    }
}

extern "C" void kernel_launch(void* const* d_in, const int* in_sizes, int n_in,
                              void* d_out, int out_size, void* d_ws, size_t ws_size,
                              hipStream_t stream) {
    const float* x  = (const float*)d_in[0];
    const float* Wq = (const float*)d_in[1];
    const float* Wk = (const float*)d_in[2];
    const float* Wv = (const float*)d_in[3];
    const float* Wo = (const float*)d_in[4];
    const float* bo = (const float*)d_in[5];
    float* out = (float*)d_out;

    char* ws = (char*)d_ws;
    u16* xb  = (u16*)ws;                              // 16 MiB, then weights contiguous
    u16* wqb = (u16*)(ws + 16777216);
    u16* wkb = wqb + 1048576;
    u16* wvb = wkb + 1048576;
    u16* wob = wvb + 1048576;
    u16* q   = (u16*)(ws + 16777216 + 8388608);       // [B][H][N][D] bf16
    u16* k   = q + 8388608;
    u16* v   = k + 8388608;
    u16* ao  = v + 8388608;                           // [B][N][H*64] bf16

    castk_all<<<3072, 256, 0, stream>>>(x, Wq, Wk, Wv, Wo, xb);

    gemm_qkv<<<dim3(ROWS / BM, 24), 256, 0, stream>>>(xb, wqb, wkb, wvb, q, k, v);

    attn<<<1024, 512, 0, stream>>>(q, k, v, ao);

    gemm_out<<<dim3(ROWS / BM, MODEL_DIM / BN), 256, 0, stream>>>(ao, wob, out, bo);
}